// Round 4
// baseline (10035.013 us; speedup 1.0000x reference)
//
#include <hip/hip_runtime.h>
#include <math.h>

// Problem constants (match reference file)
#define NNODES 100000
#define NEDGE  1600000
#define HD     64
#define INDIM  256

#define RB      32                 // rows per bucket
#define NB      3125               // NNODES / RB (exact)
#define NKEY    (4 * NB)           // 12500 (a, bucket) regions
#define CBSHIFT 12                 // 4096 cols per col-bucket (25 keys)

static constexpr size_t NP = (size_t)NNODES * HD;   // 6.4M floats per [N,H] plane
static constexpr size_t ME = (size_t)4 * NEDGE;     // 6.4M edges total

// workspace layout (floats)
static constexpr size_t XP_OFF   = 0;                 // float2 x0,x1 interleaved: 2*NP
static constexpr size_t SP_OFF   = 2 * NP;            // float2 s1,t1 interleaved: 2*NP
static constexpr size_t CRES_OFF = 4 * NP;            // s2 accumulator (f32)
static constexpr size_t CZ0_OFF  = 5 * NP;            // z0 (f32)
static constexpr size_t CZ1_OFF  = 6 * NP;            // z1 (f32)
static constexpr size_t EPK_OFF  = 7 * NP;            // int2 packed edges: 2*ME floats
static constexpr size_t CNT_OFF  = 7 * NP + 2 * ME;   // NKEY ints
static constexpr size_t OFF_OFF  = CNT_OFF + NKEY;    // NKEY ints
static constexpr size_t CUR_OFF  = OFF_OFF + NKEY;    // NKEY ints
static constexpr size_t WC_OFF   = CUR_OFF + NKEY;    // 26 floats
// total ~= 57.64M floats = 230.6 MB  (< 235.2 MB proven available in R3)

// ---------------- wave helpers ----------------
__device__ __forceinline__ float wave_bsum(float v) {
#pragma unroll
  for (int m = 1; m < 64; m <<= 1) v += __shfl_xor(v, m, 64);
  return v;
}

// ---------------- arch-weight softmax coefficients ----------------
// wc layout:
//  [0..2]   softmax(as_seq0 row0)/3      (s1 from S0[0..2])
//  [3..5]   softmax(as_seq0 row1)/3      (s2 seq part from S1[0..2])
//  [6..9]   softmax(as_res0)/4           (s2 res part from S0[0..3])
//  [10..11] softmax(as_last_seq0)/2      (z0 from S2[0..1])
//  [12..14] softmax(as_last_res0 row0)/3 (z0 from S0[0,1,3])
//  [15..17] softmax(as_last_res0 row1)/3 (z0 from S1[0,1,3])
//  [18..20] softmax(as_seq1)/3           (t1 from T0[0..2])
//  [21..22] softmax(as_last_seq1)/2      (z1 from T1[0..1])
//  [23..25] softmax(as_last_res1)/3      (z1 from T0[0,1,3])
__global__ void wcoef_kernel(const float* __restrict__ s0, const float* __restrict__ ls0,
                             const float* __restrict__ r0, const float* __restrict__ lr0,
                             const float* __restrict__ s1, const float* __restrict__ ls1,
                             const float* __restrict__ lr1, float* __restrict__ wc) {
  if (threadIdx.x != 0 || blockIdx.x != 0) return;
  auto sm2 = [](const float* a, float* o, float sc) {
    float m = fmaxf(a[0], a[1]);
    float e0 = expf(a[0] - m), e1 = expf(a[1] - m);
    float inv = sc / (e0 + e1);
    o[0] = e0 * inv; o[1] = e1 * inv;
  };
  auto sm3 = [](const float* a, float* o, float sc) {
    float m = fmaxf(a[0], fmaxf(a[1], a[2]));
    float e0 = expf(a[0] - m), e1 = expf(a[1] - m), e2 = expf(a[2] - m);
    float inv = sc / (e0 + e1 + e2);
    o[0] = e0 * inv; o[1] = e1 * inv; o[2] = e2 * inv;
  };
  auto sm4 = [](const float* a, float* o, float sc) {
    float m = fmaxf(fmaxf(a[0], a[1]), fmaxf(a[2], a[3]));
    float e0 = expf(a[0] - m), e1 = expf(a[1] - m), e2 = expf(a[2] - m), e3 = expf(a[3] - m);
    float inv = sc / (e0 + e1 + e2 + e3);
    o[0] = e0 * inv; o[1] = e1 * inv; o[2] = e2 * inv; o[3] = e3 * inv;
  };
  sm3(s0,      wc + 0,  1.f / 3.f);
  sm3(s0 + 3,  wc + 3,  1.f / 3.f);
  sm4(r0,      wc + 6,  0.25f);
  sm2(ls0,     wc + 10, 0.5f);
  sm3(lr0,     wc + 12, 1.f / 3.f);
  sm3(lr0 + 3, wc + 15, 1.f / 3.f);
  sm3(s1,      wc + 18, 1.f / 3.f);
  sm2(ls1,     wc + 21, 0.5f);
  sm3(lr1,     wc + 23, 1.f / 3.f);
}

// ---------------- per-node typed projection + both affines -> packed float2 ----------------
__global__ __launch_bounds__(256) void hid_kernel(
    const float* __restrict__ feats, const int* __restrict__ types,
    const float* __restrict__ type_W, const float* __restrict__ type_b,
    const float* __restrict__ W0, const float* __restrict__ b0,
    const float* __restrict__ W1, const float* __restrict__ b1,
    float2* __restrict__ xp) {
  int wave = threadIdx.x >> 6, lane = threadIdx.x & 63;
  int n = blockIdx.x * 4 + wave;
  if (n >= NNODES) return;
  int t = types[n];
  const float* W = type_W + (size_t)t * INDIM * HD;
  const float* f = feats + (size_t)n * INDIM;
  float f0 = f[lane], f1 = f[64 + lane], f2 = f[128 + lane], f3 = f[192 + lane];
  float acc = type_b[t * HD + lane];
#pragma unroll 8
  for (int k = 0; k < 64; k++) acc = fmaf(__shfl(f0, k, 64), W[(k)*HD + lane], acc);
#pragma unroll 8
  for (int k = 0; k < 64; k++) acc = fmaf(__shfl(f1, k, 64), W[(64 + k) * HD + lane], acc);
#pragma unroll 8
  for (int k = 0; k < 64; k++) acc = fmaf(__shfl(f2, k, 64), W[(128 + k) * HD + lane], acc);
#pragma unroll 8
  for (int k = 0; k < 64; k++) acc = fmaf(__shfl(f3, k, 64), W[(192 + k) * HD + lane], acc);
  float a0 = b0[lane], a1 = b1[lane];
#pragma unroll 8
  for (int j = 0; j < 64; j++) {
    float hv = __shfl(acc, j, 64);
    a0 = fmaf(hv, W0[j * HD + lane], a0);
    a1 = fmaf(hv, W1[j * HD + lane], a1);
  }
  xp[(size_t)n * HD + lane] = make_float2(a0, a1);
}

// ================= bucketed edge build =================
// histogram per (a, row-bucket) via LDS hist
__global__ __launch_bounds__(256) void histb_kernel(const int* __restrict__ rows,
                                                    int* __restrict__ cnt) {
  __shared__ int h[NB];
  int a = blockIdx.y;
  for (int i = threadIdx.x; i < NB; i += 256) h[i] = 0;
  __syncthreads();
  for (int e = blockIdx.x * 256 + threadIdx.x; e < NEDGE; e += gridDim.x * 256)
    atomicAdd(&h[rows[(size_t)a * NEDGE + e] >> 5], 1);
  __syncthreads();
  for (int i = threadIdx.x; i < NB; i += 256) {
    int v = h[i];
    if (v) atomicAdd(&cnt[a * NB + i], v);
  }
}

// single-block exclusive scan of NKEY counts -> off, cur
__global__ __launch_bounds__(256) void scanb_kernel(const int* __restrict__ cnt,
                                                    int* __restrict__ off,
                                                    int* __restrict__ cur) {
  __shared__ int part[256];
  int t = threadIdx.x;
  const int CH = (NKEY + 255) / 256;  // 49
  int base = t * CH;
  int s = 0;
  for (int i = 0; i < CH; i++) {
    int idx = base + i;
    if (idx < NKEY) s += cnt[idx];
  }
  part[t] = s;
  __syncthreads();
  for (int o = 1; o < 256; o <<= 1) {
    int x = (t >= o) ? part[t - o] : 0;
    __syncthreads();
    part[t] += x;
    __syncthreads();
  }
  int run = part[t] - s;  // exclusive prefix of this chunk
  for (int i = 0; i < CH; i++) {
    int idx = base + i;
    if (idx < NKEY) {
      int c = cnt[idx];
      off[idx] = run;
      cur[idx] = run;
      run += c;
    }
  }
}

// scatter edges into (a,bucket) append regions; meta = (localrow<<17) | col
__global__ __launch_bounds__(256) void binscatter_kernel(
    const int* __restrict__ rows, const int* __restrict__ cols, const float* __restrict__ vals,
    int* __restrict__ cur, int2* __restrict__ epk) {
  int a = blockIdx.y;
  int e = blockIdx.x * 256 + threadIdx.x;
  size_t idx = (size_t)a * NEDGE + e;
  int r = rows[idx], c = cols[idx];
  float v = vals[idx];
  int key = a * NB + (r >> 5);
  int pos = atomicAdd(&cur[key], 1);
  epk[pos] = make_int2(((r & 31) << 17) | c, __float_as_int(v));
}

// in-place per-region counting sort by col-bucket (col>>CBSHIFT, 25 keys)
__global__ __launch_bounds__(256) void colsort_kernel(const int* __restrict__ off,
                                                      const int* __restrict__ cnt,
                                                      int2* __restrict__ epk) {
  __shared__ int2 buf[1024];
  __shared__ int2 srt[1024];
  __shared__ int h[32];
  __shared__ int hoff[32];
  int k = blockIdx.x;
  int n = cnt[k];
  if (n <= 0 || n > 1024) return;  // capacity guard: skip sort (correctness preserved)
  int base = off[k];
  int t = threadIdx.x;
  for (int i = t; i < n; i += 256) buf[i] = epk[base + i];
  if (t < 32) h[t] = 0;
  __syncthreads();
  for (int i = t; i < n; i += 256) atomicAdd(&h[(buf[i].x & 0x1FFFF) >> CBSHIFT], 1);
  __syncthreads();
  if (t == 0) {
    int s = 0;
    for (int j = 0; j < 32; j++) { hoff[j] = s; s += h[j]; }
  }
  __syncthreads();
  for (int i = t; i < n; i += 256) {
    int cb = (buf[i].x & 0x1FFFF) >> CBSHIFT;
    int p = atomicAdd(&hoff[cb], 1);
    srt[p] = buf[i];
  }
  __syncthreads();
  for (int i = t; i < n; i += 256) epk[base + i] = srt[i];
}

// ================= SpMM stages: block per row-bucket, LDS accumulation =================
// stage 1: gather xp (x0,x1), accumulate per-adjacency S0/T0 in LDS, fold weights,
// write s1,t1 (packed), res, z0, z1.
__global__ __launch_bounds__(256) void st1_kernel(
    const int* __restrict__ off, const int* __restrict__ cnt, const int2* __restrict__ epk,
    const float2* __restrict__ xp, const float* __restrict__ wc,
    float2* __restrict__ sp, float* __restrict__ cres,
    float* __restrict__ cz0, float* __restrict__ cz1) {
  __shared__ float S0c[RB * 64], T0c[RB * 64];
  __shared__ float m_s1[RB * 64], m_t1[RB * 64], m_res[RB * 64], m_z0[RB * 64], m_z1[RB * 64];
  int b = blockIdx.x, t = threadIdx.x;
  int wave = t >> 6, lane = t & 63;
  for (int i = t; i < RB * 64; i += 256) {
    m_s1[i] = 0.f; m_t1[i] = 0.f; m_res[i] = 0.f; m_z0[i] = 0.f; m_z1[i] = 0.f;
  }
  for (int a = 0; a < 4; a++) {
    __syncthreads();
    for (int i = t; i < RB * 64; i += 256) { S0c[i] = 0.f; T0c[i] = 0.f; }
    __syncthreads();
    int key = a * NB + b;
    int base = off[key], n = cnt[key];
    int i = wave;
    for (; i + 4 < n; i += 8) {
      int2 p0 = epk[base + i], p1 = epk[base + i + 4];
      int c0 = p0.x & 0x1FFFF, l0 = p0.x >> 17;
      int c1 = p1.x & 0x1FFFF, l1 = p1.x >> 17;
      float v0 = __int_as_float(p0.y), v1 = __int_as_float(p1.y);
      float2 g0 = xp[(size_t)c0 * 64 + lane];
      float2 g1 = xp[(size_t)c1 * 64 + lane];
      atomicAdd(&S0c[l0 * 64 + lane], v0 * g0.x);
      atomicAdd(&T0c[l0 * 64 + lane], v0 * g0.y);
      atomicAdd(&S0c[l1 * 64 + lane], v1 * g1.x);
      atomicAdd(&T0c[l1 * 64 + lane], v1 * g1.y);
    }
    for (; i < n; i += 4) {
      int2 p = epk[base + i];
      int c = p.x & 0x1FFFF, lr = p.x >> 17;
      float v = __int_as_float(p.y);
      float2 g = xp[(size_t)c * 64 + lane];
      atomicAdd(&S0c[lr * 64 + lane], v * g.x);
      atomicAdd(&T0c[lr * 64 + lane], v * g.y);
    }
    __syncthreads();
    float w_s1  = (a < 3) ? wc[a] : 0.f;
    float w_res = wc[6 + a];
    float w_z0  = (a == 3) ? wc[14] : ((a < 2) ? wc[12 + a] : 0.f);
    float w_t1  = (a < 3) ? wc[18 + a] : 0.f;
    float w_z1  = (a == 3) ? wc[25] : ((a < 2) ? wc[23 + a] : 0.f);
    for (int i2 = t; i2 < RB * 64; i2 += 256) {
      float s = S0c[i2], tt = T0c[i2];
      m_s1[i2]  += w_s1 * s;
      m_res[i2] += w_res * s;
      m_z0[i2]  += w_z0 * s;
      m_t1[i2]  += w_t1 * tt;
      m_z1[i2]  += w_z1 * tt;
    }
  }
  __syncthreads();
  size_t rb = (size_t)b * RB * 64;
  for (int i = t; i < RB * 64; i += 256) {
    sp[rb + i] = make_float2(m_s1[i], m_t1[i]);
    cres[rb + i] = m_res[i];
    cz0[rb + i] = m_z0[i];
    cz1[rb + i] = m_z1[i];
  }
}

// stage 2: gather sp (s1,t1); fold into cres (s2 seq part), z0, z1 (global RMW add)
__global__ __launch_bounds__(256) void st2_kernel(
    const int* __restrict__ off, const int* __restrict__ cnt, const int2* __restrict__ epk,
    const float2* __restrict__ sp, const float* __restrict__ wc,
    float* __restrict__ cres, float* __restrict__ cz0, float* __restrict__ cz1) {
  __shared__ float S1c[RB * 64], T1c[RB * 64];
  __shared__ float d_res[RB * 64], d_z0[RB * 64], d_z1[RB * 64];
  int b = blockIdx.x, t = threadIdx.x;
  int wave = t >> 6, lane = t & 63;
  for (int i = t; i < RB * 64; i += 256) { d_res[i] = 0.f; d_z0[i] = 0.f; d_z1[i] = 0.f; }
  for (int a = 0; a < 4; a++) {
    __syncthreads();
    for (int i = t; i < RB * 64; i += 256) { S1c[i] = 0.f; T1c[i] = 0.f; }
    __syncthreads();
    int key = a * NB + b;
    int base = off[key], n = cnt[key];
    bool needT = (a < 2);
    int i = wave;
    for (; i + 4 < n; i += 8) {
      int2 p0 = epk[base + i], p1 = epk[base + i + 4];
      int c0 = p0.x & 0x1FFFF, l0 = p0.x >> 17;
      int c1 = p1.x & 0x1FFFF, l1 = p1.x >> 17;
      float v0 = __int_as_float(p0.y), v1 = __int_as_float(p1.y);
      float2 g0 = sp[(size_t)c0 * 64 + lane];
      float2 g1 = sp[(size_t)c1 * 64 + lane];
      atomicAdd(&S1c[l0 * 64 + lane], v0 * g0.x);
      atomicAdd(&S1c[l1 * 64 + lane], v1 * g1.x);
      if (needT) {
        atomicAdd(&T1c[l0 * 64 + lane], v0 * g0.y);
        atomicAdd(&T1c[l1 * 64 + lane], v1 * g1.y);
      }
    }
    for (; i < n; i += 4) {
      int2 p = epk[base + i];
      int c = p.x & 0x1FFFF, lr = p.x >> 17;
      float v = __int_as_float(p.y);
      float2 g = sp[(size_t)c * 64 + lane];
      atomicAdd(&S1c[lr * 64 + lane], v * g.x);
      if (needT) atomicAdd(&T1c[lr * 64 + lane], v * g.y);
    }
    __syncthreads();
    float w_seq = (a < 3) ? wc[3 + a] : 0.f;
    float w_z0  = (a == 3) ? wc[17] : ((a < 2) ? wc[15 + a] : 0.f);
    float w_z1  = (a < 2) ? wc[21 + a] : 0.f;
    for (int i2 = t; i2 < RB * 64; i2 += 256) {
      float s = S1c[i2], tt = T1c[i2];
      d_res[i2] += w_seq * s;
      d_z0[i2]  += w_z0 * s;
      d_z1[i2]  += w_z1 * tt;
    }
  }
  __syncthreads();
  size_t rb = (size_t)b * RB * 64;
  for (int i = t; i < RB * 64; i += 256) {
    cres[rb + i] += d_res[i];
    cz0[rb + i] += d_z0[i];
    cz1[rb + i] += d_z1[i];
  }
}

// stage 3: gather s2 (=cres) on adjs 0,1 with weight folded; add into cz0
__global__ __launch_bounds__(256) void st3_kernel(
    const int* __restrict__ off, const int* __restrict__ cnt, const int2* __restrict__ epk,
    const float* __restrict__ s2, const float* __restrict__ wc, float* __restrict__ cz0) {
  __shared__ float dz[RB * 64];
  int b = blockIdx.x, t = threadIdx.x;
  int wave = t >> 6, lane = t & 63;
  for (int i = t; i < RB * 64; i += 256) dz[i] = 0.f;
  __syncthreads();
  for (int a = 0; a < 2; a++) {
    int key = a * NB + b;
    int base = off[key], n = cnt[key];
    float w = wc[10 + a];
    int i = wave;
    for (; i + 4 < n; i += 8) {
      int2 p0 = epk[base + i], p1 = epk[base + i + 4];
      int c0 = p0.x & 0x1FFFF, l0 = p0.x >> 17;
      int c1 = p1.x & 0x1FFFF, l1 = p1.x >> 17;
      float v0 = __int_as_float(p0.y), v1 = __int_as_float(p1.y);
      float g0 = s2[(size_t)c0 * 64 + lane];
      float g1 = s2[(size_t)c1 * 64 + lane];
      atomicAdd(&dz[l0 * 64 + lane], w * v0 * g0);
      atomicAdd(&dz[l1 * 64 + lane], w * v1 * g1);
    }
    for (; i < n; i += 4) {
      int2 p = epk[base + i];
      int c = p.x & 0x1FFFF, lr = p.x >> 17;
      float v = __int_as_float(p.y);
      atomicAdd(&dz[lr * 64 + lane], w * v * s2[(size_t)c * 64 + lane]);
    }
    __syncthreads();
  }
  size_t rb = (size_t)b * RB * 64;
  for (int i = t; i < RB * 64; i += 256) cz0[rb + i] += dz[i];
}

// ---------------- final: LN+gelu both cells, semantic attention, classifier ----------------
__global__ __launch_bounds__(256) void final_kernel(
    const float* __restrict__ cz0, const float* __restrict__ cz1,
    const float* __restrict__ attn1_W, const float* __restrict__ attn1_b,
    const float* __restrict__ attn2_W, const float* __restrict__ attn2_b,
    const float* __restrict__ cls_W, const float* __restrict__ cls_b,
    float* __restrict__ out) {
  int wave = threadIdx.x >> 6, lane = threadIdx.x & 63;
  int n = blockIdx.x * 4 + wave;
  if (n >= NNODES) return;
  size_t idx = (size_t)n * HD + lane;

  float z0 = cz0[idx];
  float z1 = cz1[idx];

  float m0 = wave_bsum(z0) * (1.f / 64.f);
  float dv0 = z0 - m0;
  float var0 = wave_bsum(dv0 * dv0) * (1.f / 64.f);
  float y0 = dv0 * rsqrtf(var0 + 1e-5f);
  float g0 = 0.5f * y0 * (1.f + erff(y0 * 0.70710678118654752f));

  float m1 = wave_bsum(z1) * (1.f / 64.f);
  float dv1 = z1 - m1;
  float var1 = wave_bsum(dv1 * dv1) * (1.f / 64.f);
  float y1 = dv1 * rsqrtf(var1 + 1e-5f);
  float g1 = 0.5f * y1 * (1.f + erff(y1 * 0.70710678118654752f));

  float t0 = attn1_b[lane], t1 = attn1_b[lane];
#pragma unroll 8
  for (int j = 0; j < 64; j++) {
    float w = attn1_W[j * HD + lane];
    t0 = fmaf(__shfl(g0, j, 64), w, t0);
    t1 = fmaf(__shfl(g1, j, 64), w, t1);
  }
  t0 = tanhf(t0);
  t1 = tanhf(t1);
  float aw = attn2_W[lane];
  float a0 = wave_bsum(t0 * aw) + attn2_b[0];
  float a1 = wave_bsum(t1 * aw) + attn2_b[0];
  float mx = fmaxf(a0, a1);
  float e0 = expf(a0 - mx), e1 = expf(a1 - mx);
  float inv = 1.f / (e0 + e1);
  float p0 = e0 * inv, p1 = e1 * inv;
  float o = p0 * g0 + p1 * g1;

#pragma unroll
  for (int k = 0; k < 8; k++) {
    float s = wave_bsum(o * cls_W[lane * 8 + k]);
    if (lane == k) out[(size_t)n * 8 + k] = s + cls_b[k];
  }
}

extern "C" void kernel_launch(void* const* d_in, const int* in_sizes, int n_in,
                              void* d_out, int out_size, void* d_ws, size_t ws_size,
                              hipStream_t stream) {
  const float* node_feats   = (const float*)d_in[0];
  const int*   node_types   = (const int*)d_in[1];
  const int*   adj_rows     = (const int*)d_in[2];
  const int*   adj_cols     = (const int*)d_in[3];
  const float* adj_vals     = (const float*)d_in[4];
  const float* type_W       = (const float*)d_in[5];
  const float* type_b       = (const float*)d_in[6];
  const float* aW0          = (const float*)d_in[7];
  const float* ab0          = (const float*)d_in[8];
  const float* aW1          = (const float*)d_in[9];
  const float* ab1          = (const float*)d_in[10];
  const float* as_seq0      = (const float*)d_in[11];
  const float* as_last_seq0 = (const float*)d_in[12];
  const float* as_res0      = (const float*)d_in[13];
  const float* as_last_res0 = (const float*)d_in[14];
  const float* as_seq1      = (const float*)d_in[15];
  const float* as_last_seq1 = (const float*)d_in[16];
  const float* as_last_res1 = (const float*)d_in[17];
  const float* attn1_W      = (const float*)d_in[18];
  const float* attn1_b      = (const float*)d_in[19];
  const float* attn2_W      = (const float*)d_in[20];
  const float* attn2_b      = (const float*)d_in[21];
  const float* cls_W        = (const float*)d_in[22];
  const float* cls_b        = (const float*)d_in[23];
  float* out = (float*)d_out;
  float* ws = (float*)d_ws;

  float2* xp  = (float2*)(ws + XP_OFF);
  float2* sp  = (float2*)(ws + SP_OFF);
  float* cres = ws + CRES_OFF;
  float* cz0  = ws + CZ0_OFF;
  float* cz1  = ws + CZ1_OFF;
  int2*  epk  = (int2*)(ws + EPK_OFF);
  int*   cnt  = (int*)(ws + CNT_OFF);
  int*   off  = (int*)(ws + OFF_OFF);
  int*   cur  = (int*)(ws + CUR_OFF);
  float* wc   = ws + WC_OFF;

  hipMemsetAsync(cnt, 0, NKEY * sizeof(int), stream);

  wcoef_kernel<<<1, 64, 0, stream>>>(as_seq0, as_last_seq0, as_res0, as_last_res0,
                                     as_seq1, as_last_seq1, as_last_res1, wc);

  hid_kernel<<<NNODES / 4, 256, 0, stream>>>(node_feats, node_types, type_W, type_b,
                                             aW0, ab0, aW1, ab1, xp);

  // edge bucketing: hist -> scan -> scatter -> in-place col-sort
  histb_kernel<<<dim3(64, 4), 256, 0, stream>>>(adj_rows, cnt);
  scanb_kernel<<<1, 256, 0, stream>>>(cnt, off, cur);
  binscatter_kernel<<<dim3(NEDGE / 256, 4), 256, 0, stream>>>(adj_rows, adj_cols, adj_vals,
                                                              cur, epk);
  colsort_kernel<<<NKEY, 256, 0, stream>>>(off, cnt, epk);

  // SpMM stages (LDS accumulation, no global atomics)
  st1_kernel<<<NB, 256, 0, stream>>>(off, cnt, epk, xp, wc, sp, cres, cz0, cz1);
  st2_kernel<<<NB, 256, 0, stream>>>(off, cnt, epk, sp, wc, cres, cz0, cz1);
  st3_kernel<<<NB, 256, 0, stream>>>(off, cnt, epk, cres, wc, cz0);

  final_kernel<<<NNODES / 4, 256, 0, stream>>>(cz0, cz1,
                                               attn1_W, attn1_b, attn2_W, attn2_b,
                                               cls_W, cls_b, out);
}

// Round 5
// 2379.464 us; speedup vs baseline: 4.2173x; 4.2173x over previous
//
#include <hip/hip_runtime.h>
#include <math.h>

// Problem constants (match reference file)
#define NNODES 100000
#define NEDGE  1600000
#define HD     64
#define INDIM  256

#define RB   32                 // rows per bucket
#define NB   3125               // NNODES / RB (exact)
#define NKEY (4 * NB)           // 12500 (a, bucket) regions
#define CAP  1024               // edges per LDS sort chunk

static constexpr size_t NP = (size_t)NNODES * HD;   // 6.4M floats per [N,H] plane
static constexpr size_t ME = (size_t)4 * NEDGE;     // 6.4M edges total

// workspace layout (floats)
static constexpr size_t XP_OFF   = 0;                 // float2 x0,x1 interleaved: 2*NP
static constexpr size_t SP_OFF   = 2 * NP;            // float2 s1,t1 interleaved: 2*NP
static constexpr size_t CRES_OFF = 4 * NP;            // s2 accumulator (f32)
static constexpr size_t CZ0_OFF  = 5 * NP;            // z0 (f32)
static constexpr size_t CZ1_OFF  = 6 * NP;            // z1 (f32)
static constexpr size_t EPK_OFF  = 7 * NP;            // int2 packed edges: 2*ME floats
static constexpr size_t CNT_OFF  = 7 * NP + 2 * ME;   // NKEY ints
static constexpr size_t OFF_OFF  = CNT_OFF + NKEY;    // NKEY ints
static constexpr size_t CUR_OFF  = OFF_OFF + NKEY;    // NKEY ints
static constexpr size_t WC_OFF   = CUR_OFF + NKEY;    // 26 floats
// total ~= 230.6 MB (< 235.2 MB proven available in R3)

// ---------------- wave helpers ----------------
__device__ __forceinline__ float wave_bsum(float v) {
#pragma unroll
  for (int m = 1; m < 64; m <<= 1) v += __shfl_xor(v, m, 64);
  return v;
}

// ---------------- arch-weight softmax coefficients ----------------
// wc layout:
//  [0..2]   softmax(as_seq0 row0)/3      (s1 from S0[0..2])
//  [3..5]   softmax(as_seq0 row1)/3      (s2 seq part from S1[0..2])
//  [6..9]   softmax(as_res0)/4           (s2 res part from S0[0..3])
//  [10..11] softmax(as_last_seq0)/2      (z0 from S2[0..1])
//  [12..14] softmax(as_last_res0 row0)/3 (z0 from S0[0,1,3])
//  [15..17] softmax(as_last_res0 row1)/3 (z0 from S1[0,1,3])
//  [18..20] softmax(as_seq1)/3           (t1 from T0[0..2])
//  [21..22] softmax(as_last_seq1)/2      (z1 from T1[0..1])
//  [23..25] softmax(as_last_res1)/3      (z1 from T0[0,1,3])
__global__ void wcoef_kernel(const float* __restrict__ s0, const float* __restrict__ ls0,
                             const float* __restrict__ r0, const float* __restrict__ lr0,
                             const float* __restrict__ s1, const float* __restrict__ ls1,
                             const float* __restrict__ lr1, float* __restrict__ wc) {
  if (threadIdx.x != 0 || blockIdx.x != 0) return;
  auto sm2 = [](const float* a, float* o, float sc) {
    float m = fmaxf(a[0], a[1]);
    float e0 = expf(a[0] - m), e1 = expf(a[1] - m);
    float inv = sc / (e0 + e1);
    o[0] = e0 * inv; o[1] = e1 * inv;
  };
  auto sm3 = [](const float* a, float* o, float sc) {
    float m = fmaxf(a[0], fmaxf(a[1], a[2]));
    float e0 = expf(a[0] - m), e1 = expf(a[1] - m), e2 = expf(a[2] - m);
    float inv = sc / (e0 + e1 + e2);
    o[0] = e0 * inv; o[1] = e1 * inv; o[2] = e2 * inv;
  };
  auto sm4 = [](const float* a, float* o, float sc) {
    float m = fmaxf(fmaxf(a[0], a[1]), fmaxf(a[2], a[3]));
    float e0 = expf(a[0] - m), e1 = expf(a[1] - m), e2 = expf(a[2] - m), e3 = expf(a[3] - m);
    float inv = sc / (e0 + e1 + e2 + e3);
    o[0] = e0 * inv; o[1] = e1 * inv; o[2] = e2 * inv; o[3] = e3 * inv;
  };
  sm3(s0,      wc + 0,  1.f / 3.f);
  sm3(s0 + 3,  wc + 3,  1.f / 3.f);
  sm4(r0,      wc + 6,  0.25f);
  sm2(ls0,     wc + 10, 0.5f);
  sm3(lr0,     wc + 12, 1.f / 3.f);
  sm3(lr0 + 3, wc + 15, 1.f / 3.f);
  sm3(s1,      wc + 18, 1.f / 3.f);
  sm2(ls1,     wc + 21, 0.5f);
  sm3(lr1,     wc + 23, 1.f / 3.f);
}

// ---------------- per-node typed projection + both affines -> packed float2 ----------------
__global__ __launch_bounds__(256) void hid_kernel(
    const float* __restrict__ feats, const int* __restrict__ types,
    const float* __restrict__ type_W, const float* __restrict__ type_b,
    const float* __restrict__ W0, const float* __restrict__ b0,
    const float* __restrict__ W1, const float* __restrict__ b1,
    float2* __restrict__ xp) {
  int wave = threadIdx.x >> 6, lane = threadIdx.x & 63;
  int n = blockIdx.x * 4 + wave;
  if (n >= NNODES) return;
  int t = types[n];
  const float* W = type_W + (size_t)t * INDIM * HD;
  const float* f = feats + (size_t)n * INDIM;
  float f0 = f[lane], f1 = f[64 + lane], f2 = f[128 + lane], f3 = f[192 + lane];
  float acc = type_b[t * HD + lane];
#pragma unroll 8
  for (int k = 0; k < 64; k++) acc = fmaf(__shfl(f0, k, 64), W[(k)*HD + lane], acc);
#pragma unroll 8
  for (int k = 0; k < 64; k++) acc = fmaf(__shfl(f1, k, 64), W[(64 + k) * HD + lane], acc);
#pragma unroll 8
  for (int k = 0; k < 64; k++) acc = fmaf(__shfl(f2, k, 64), W[(128 + k) * HD + lane], acc);
#pragma unroll 8
  for (int k = 0; k < 64; k++) acc = fmaf(__shfl(f3, k, 64), W[(192 + k) * HD + lane], acc);
  float a0 = b0[lane], a1 = b1[lane];
#pragma unroll 8
  for (int j = 0; j < 64; j++) {
    float hv = __shfl(acc, j, 64);
    a0 = fmaf(hv, W0[j * HD + lane], a0);
    a1 = fmaf(hv, W1[j * HD + lane], a1);
  }
  xp[(size_t)n * HD + lane] = make_float2(a0, a1);
}

// ================= bucketed edge build (proven in R4) =================
__global__ __launch_bounds__(256) void histb_kernel(const int* __restrict__ rows,
                                                    int* __restrict__ cnt) {
  __shared__ int h[NB];
  int a = blockIdx.y;
  for (int i = threadIdx.x; i < NB; i += 256) h[i] = 0;
  __syncthreads();
  for (int e = blockIdx.x * 256 + threadIdx.x; e < NEDGE; e += gridDim.x * 256)
    atomicAdd(&h[rows[(size_t)a * NEDGE + e] >> 5], 1);
  __syncthreads();
  for (int i = threadIdx.x; i < NB; i += 256) {
    int v = h[i];
    if (v) atomicAdd(&cnt[a * NB + i], v);
  }
}

__global__ __launch_bounds__(256) void scanb_kernel(const int* __restrict__ cnt,
                                                    int* __restrict__ off,
                                                    int* __restrict__ cur) {
  __shared__ int part[256];
  int t = threadIdx.x;
  const int CH = (NKEY + 255) / 256;  // 49
  int base = t * CH;
  int s = 0;
  for (int i = 0; i < CH; i++) {
    int idx = base + i;
    if (idx < NKEY) s += cnt[idx];
  }
  part[t] = s;
  __syncthreads();
  for (int o = 1; o < 256; o <<= 1) {
    int x = (t >= o) ? part[t - o] : 0;
    __syncthreads();
    part[t] += x;
    __syncthreads();
  }
  int run = part[t] - s;  // exclusive prefix of this chunk
  for (int i = 0; i < CH; i++) {
    int idx = base + i;
    if (idx < NKEY) {
      int c = cnt[idx];
      off[idx] = run;
      cur[idx] = run;
      run += c;
    }
  }
}

// scatter edges into (a,bucket) append regions; meta = (localrow<<17) | col
__global__ __launch_bounds__(256) void binscatter_kernel(
    const int* __restrict__ rows, const int* __restrict__ cols, const float* __restrict__ vals,
    int* __restrict__ cur, int2* __restrict__ epk) {
  int a = blockIdx.y;
  int e = blockIdx.x * 256 + threadIdx.x;
  size_t idx = (size_t)a * NEDGE + e;
  int r = rows[idx], c = cols[idx];
  float v = vals[idx];
  int key = a * NB + (r >> 5);
  int pos = atomicAdd(&cur[key], 1);
  epk[pos] = make_int2(((r & 31) << 17) | c, __float_as_int(v));
}

// ================= SpMM stages: block-per-bucket, on-the-fly LDS row-sort,
// register accumulation, no atomics beyond block-local LDS sort bookkeeping ===========

// shared sort scaffold used by all stages
struct SortSh {
  int   smeta[CAP];
  float sval[CAP];
  int   rcnt[RB];
  int   roff[RB];
  int   rcur[RB];
};

// sorts epk[base+start .. base+start+m) by local row into sh; all threads participate
__device__ __forceinline__ void sort_chunk(SortSh& sh, const int2* __restrict__ epk,
                                           int base, int start, int m,
                                           int t, int wv, int lane) {
  __syncthreads();  // previous consumers done with sh
  if (t < RB) sh.rcnt[t] = 0;
  __syncthreads();
  int em[4]; float ev[4];
  int cnt_local = 0;
#pragma unroll
  for (int j = 0; j < 4; j++) {
    int i = t + j * 256;
    if (i < m) {
      int2 p = epk[base + start + i];
      em[cnt_local] = p.x;
      ev[cnt_local] = __int_as_float(p.y);
      cnt_local++;
      atomicAdd(&sh.rcnt[p.x >> 17], 1);
    }
  }
  __syncthreads();
  if (wv == 0) {
    int v = (lane < RB) ? sh.rcnt[lane] : 0;
    int incl = v;
#pragma unroll
    for (int o = 1; o < RB; o <<= 1) {
      int x = __shfl_up(incl, o, 64);
      if (lane >= o) incl += x;
    }
    if (lane < RB) {
      sh.roff[lane] = incl - v;
      sh.rcur[lane] = incl - v;
    }
  }
  __syncthreads();
#pragma unroll
  for (int j = 0; j < 4; j++) {
    if (j < cnt_local) {
      int mm = em[j];
      int p = atomicAdd(&sh.rcur[mm >> 17], 1);
      sh.smeta[p] = mm;
      sh.sval[p] = ev[j];
    }
  }
  __syncthreads();
}

// stage 1: gather xp (x0,x1); write s1,t1 (packed), res, z0, z1
__global__ __launch_bounds__(256) void st1_kernel(
    const int* __restrict__ off, const int* __restrict__ cnt, const int2* __restrict__ epk,
    const float2* __restrict__ xp, const float* __restrict__ wc,
    float2* __restrict__ sp, float* __restrict__ cres,
    float* __restrict__ cz0, float* __restrict__ cz1) {
  __shared__ SortSh sh;
  int b = blockIdx.x, t = threadIdx.x;
  int wv = t >> 6, lane = t & 63;
  float as1[8], at1[8], ares[8], az0[8], az1[8];
#pragma unroll
  for (int r = 0; r < 8; r++) { as1[r] = 0.f; at1[r] = 0.f; ares[r] = 0.f; az0[r] = 0.f; az1[r] = 0.f; }
  for (int a = 0; a < 4; a++) {
    int key = a * NB + b;
    int base = off[key], n = cnt[key];
    float w_s1  = (a < 3) ? wc[a] : 0.f;
    float w_res = wc[6 + a];
    float w_z0  = (a == 3) ? wc[14] : ((a < 2) ? wc[12 + a] : 0.f);
    float w_t1  = (a < 3) ? wc[18 + a] : 0.f;
    float w_z1  = (a == 3) ? wc[25] : ((a < 2) ? wc[23 + a] : 0.f);
    for (int start = 0; start < n; start += CAP) {
      int m = min(CAP, n - start);
      sort_chunk(sh, epk, base, start, m, t, wv, lane);
#pragma unroll
      for (int r8 = 0; r8 < 8; r8++) {
        int r = wv * 8 + r8;
        int s0 = sh.roff[r], e0 = s0 + sh.rcnt[r];
        float accs = 0.f, acct = 0.f;
        int i = s0;
        for (; i + 1 < e0; i += 2) {
          int m0 = sh.smeta[i], m1 = sh.smeta[i + 1];
          float v0 = sh.sval[i], v1 = sh.sval[i + 1];
          float2 g0 = xp[(size_t)(m0 & 0x1FFFF) * 64 + lane];
          float2 g1 = xp[(size_t)(m1 & 0x1FFFF) * 64 + lane];
          accs = fmaf(v0, g0.x, accs); acct = fmaf(v0, g0.y, acct);
          accs = fmaf(v1, g1.x, accs); acct = fmaf(v1, g1.y, acct);
        }
        if (i < e0) {
          int m0 = sh.smeta[i];
          float v0 = sh.sval[i];
          float2 g0 = xp[(size_t)(m0 & 0x1FFFF) * 64 + lane];
          accs = fmaf(v0, g0.x, accs); acct = fmaf(v0, g0.y, acct);
        }
        as1[r8]  = fmaf(w_s1, accs, as1[r8]);
        ares[r8] = fmaf(w_res, accs, ares[r8]);
        az0[r8]  = fmaf(w_z0, accs, az0[r8]);
        at1[r8]  = fmaf(w_t1, acct, at1[r8]);
        az1[r8]  = fmaf(w_z1, acct, az1[r8]);
      }
    }
  }
  int rowbase = b * RB + wv * 8;
#pragma unroll
  for (int r8 = 0; r8 < 8; r8++) {
    size_t o = (size_t)(rowbase + r8) * 64 + lane;
    sp[o] = make_float2(as1[r8], at1[r8]);
    cres[o] = ares[r8];
    cz0[o] = az0[r8];
    cz1[o] = az1[r8];
  }
}

// stage 2: gather sp (s1,t1); add into cres (s2 seq), cz0, cz1
__global__ __launch_bounds__(256) void st2_kernel(
    const int* __restrict__ off, const int* __restrict__ cnt, const int2* __restrict__ epk,
    const float2* __restrict__ sp, const float* __restrict__ wc,
    float* __restrict__ cres, float* __restrict__ cz0, float* __restrict__ cz1) {
  __shared__ SortSh sh;
  int b = blockIdx.x, t = threadIdx.x;
  int wv = t >> 6, lane = t & 63;
  float dres[8], dz0[8], dz1[8];
#pragma unroll
  for (int r = 0; r < 8; r++) { dres[r] = 0.f; dz0[r] = 0.f; dz1[r] = 0.f; }
  for (int a = 0; a < 4; a++) {
    int key = a * NB + b;
    int base = off[key], n = cnt[key];
    float w_seq = (a < 3) ? wc[3 + a] : 0.f;
    float w_z0  = (a == 3) ? wc[17] : ((a < 2) ? wc[15 + a] : 0.f);
    float w_z1  = (a < 2) ? wc[21 + a] : 0.f;
    for (int start = 0; start < n; start += CAP) {
      int m = min(CAP, n - start);
      sort_chunk(sh, epk, base, start, m, t, wv, lane);
#pragma unroll
      for (int r8 = 0; r8 < 8; r8++) {
        int r = wv * 8 + r8;
        int s0 = sh.roff[r], e0 = s0 + sh.rcnt[r];
        float accs = 0.f, acct = 0.f;
        int i = s0;
        for (; i + 1 < e0; i += 2) {
          int m0 = sh.smeta[i], m1 = sh.smeta[i + 1];
          float v0 = sh.sval[i], v1 = sh.sval[i + 1];
          float2 g0 = sp[(size_t)(m0 & 0x1FFFF) * 64 + lane];
          float2 g1 = sp[(size_t)(m1 & 0x1FFFF) * 64 + lane];
          accs = fmaf(v0, g0.x, accs); acct = fmaf(v0, g0.y, acct);
          accs = fmaf(v1, g1.x, accs); acct = fmaf(v1, g1.y, acct);
        }
        if (i < e0) {
          int m0 = sh.smeta[i];
          float v0 = sh.sval[i];
          float2 g0 = sp[(size_t)(m0 & 0x1FFFF) * 64 + lane];
          accs = fmaf(v0, g0.x, accs); acct = fmaf(v0, g0.y, acct);
        }
        dres[r8] = fmaf(w_seq, accs, dres[r8]);
        dz0[r8]  = fmaf(w_z0, accs, dz0[r8]);
        dz1[r8]  = fmaf(w_z1, acct, dz1[r8]);
      }
    }
  }
  int rowbase = b * RB + wv * 8;
#pragma unroll
  for (int r8 = 0; r8 < 8; r8++) {
    size_t o = (size_t)(rowbase + r8) * 64 + lane;
    cres[o] += dres[r8];
    cz0[o] += dz0[r8];
    cz1[o] += dz1[r8];
  }
}

// stage 3: gather s2 (=cres) on adjs 0,1 (weight folded); add into cz0
__global__ __launch_bounds__(256) void st3_kernel(
    const int* __restrict__ off, const int* __restrict__ cnt, const int2* __restrict__ epk,
    const float* __restrict__ s2, const float* __restrict__ wc, float* __restrict__ cz0) {
  __shared__ SortSh sh;
  int b = blockIdx.x, t = threadIdx.x;
  int wv = t >> 6, lane = t & 63;
  float dz[8];
#pragma unroll
  for (int r = 0; r < 8; r++) dz[r] = 0.f;
  for (int a = 0; a < 2; a++) {
    int key = a * NB + b;
    int base = off[key], n = cnt[key];
    float w = wc[10 + a];
    for (int start = 0; start < n; start += CAP) {
      int m = min(CAP, n - start);
      sort_chunk(sh, epk, base, start, m, t, wv, lane);
#pragma unroll
      for (int r8 = 0; r8 < 8; r8++) {
        int r = wv * 8 + r8;
        int s0 = sh.roff[r], e0 = s0 + sh.rcnt[r];
        float accs = 0.f;
        int i = s0;
        for (; i + 1 < e0; i += 2) {
          int m0 = sh.smeta[i], m1 = sh.smeta[i + 1];
          float v0 = sh.sval[i], v1 = sh.sval[i + 1];
          accs = fmaf(v0, s2[(size_t)(m0 & 0x1FFFF) * 64 + lane], accs);
          accs = fmaf(v1, s2[(size_t)(m1 & 0x1FFFF) * 64 + lane], accs);
        }
        if (i < e0) {
          accs = fmaf(sh.sval[i], s2[(size_t)(sh.smeta[i] & 0x1FFFF) * 64 + lane], accs);
        }
        dz[r8] = fmaf(w, accs, dz[r8]);
      }
    }
  }
  int rowbase = b * RB + wv * 8;
#pragma unroll
  for (int r8 = 0; r8 < 8; r8++) {
    size_t o = (size_t)(rowbase + r8) * 64 + lane;
    cz0[o] += dz[r8];
  }
}

// ---------------- final: LN+gelu both cells, semantic attention, classifier ----------------
__global__ __launch_bounds__(256) void final_kernel(
    const float* __restrict__ cz0, const float* __restrict__ cz1,
    const float* __restrict__ attn1_W, const float* __restrict__ attn1_b,
    const float* __restrict__ attn2_W, const float* __restrict__ attn2_b,
    const float* __restrict__ cls_W, const float* __restrict__ cls_b,
    float* __restrict__ out) {
  int wave = threadIdx.x >> 6, lane = threadIdx.x & 63;
  int n = blockIdx.x * 4 + wave;
  if (n >= NNODES) return;
  size_t idx = (size_t)n * HD + lane;

  float z0 = cz0[idx];
  float z1 = cz1[idx];

  float m0 = wave_bsum(z0) * (1.f / 64.f);
  float dv0 = z0 - m0;
  float var0 = wave_bsum(dv0 * dv0) * (1.f / 64.f);
  float y0 = dv0 * rsqrtf(var0 + 1e-5f);
  float g0 = 0.5f * y0 * (1.f + erff(y0 * 0.70710678118654752f));

  float m1 = wave_bsum(z1) * (1.f / 64.f);
  float dv1 = z1 - m1;
  float var1 = wave_bsum(dv1 * dv1) * (1.f / 64.f);
  float y1 = dv1 * rsqrtf(var1 + 1e-5f);
  float g1 = 0.5f * y1 * (1.f + erff(y1 * 0.70710678118654752f));

  float t0 = attn1_b[lane], t1 = attn1_b[lane];
#pragma unroll 8
  for (int j = 0; j < 64; j++) {
    float w = attn1_W[j * HD + lane];
    t0 = fmaf(__shfl(g0, j, 64), w, t0);
    t1 = fmaf(__shfl(g1, j, 64), w, t1);
  }
  t0 = tanhf(t0);
  t1 = tanhf(t1);
  float aw = attn2_W[lane];
  float a0 = wave_bsum(t0 * aw) + attn2_b[0];
  float a1 = wave_bsum(t1 * aw) + attn2_b[0];
  float mx = fmaxf(a0, a1);
  float e0 = expf(a0 - mx), e1 = expf(a1 - mx);
  float inv = 1.f / (e0 + e1);
  float p0 = e0 * inv, p1 = e1 * inv;
  float o = p0 * g0 + p1 * g1;

#pragma unroll
  for (int k = 0; k < 8; k++) {
    float s = wave_bsum(o * cls_W[lane * 8 + k]);
    if (lane == k) out[(size_t)n * 8 + k] = s + cls_b[k];
  }
}

extern "C" void kernel_launch(void* const* d_in, const int* in_sizes, int n_in,
                              void* d_out, int out_size, void* d_ws, size_t ws_size,
                              hipStream_t stream) {
  const float* node_feats   = (const float*)d_in[0];
  const int*   node_types   = (const int*)d_in[1];
  const int*   adj_rows     = (const int*)d_in[2];
  const int*   adj_cols     = (const int*)d_in[3];
  const float* adj_vals     = (const float*)d_in[4];
  const float* type_W       = (const float*)d_in[5];
  const float* type_b       = (const float*)d_in[6];
  const float* aW0          = (const float*)d_in[7];
  const float* ab0          = (const float*)d_in[8];
  const float* aW1          = (const float*)d_in[9];
  const float* ab1          = (const float*)d_in[10];
  const float* as_seq0      = (const float*)d_in[11];
  const float* as_last_seq0 = (const float*)d_in[12];
  const float* as_res0      = (const float*)d_in[13];
  const float* as_last_res0 = (const float*)d_in[14];
  const float* as_seq1      = (const float*)d_in[15];
  const float* as_last_seq1 = (const float*)d_in[16];
  const float* as_last_res1 = (const float*)d_in[17];
  const float* attn1_W      = (const float*)d_in[18];
  const float* attn1_b      = (const float*)d_in[19];
  const float* attn2_W      = (const float*)d_in[20];
  const float* attn2_b      = (const float*)d_in[21];
  const float* cls_W        = (const float*)d_in[22];
  const float* cls_b        = (const float*)d_in[23];
  float* out = (float*)d_out;
  float* ws = (float*)d_ws;

  float2* xp  = (float2*)(ws + XP_OFF);
  float2* sp  = (float2*)(ws + SP_OFF);
  float* cres = ws + CRES_OFF;
  float* cz0  = ws + CZ0_OFF;
  float* cz1  = ws + CZ1_OFF;
  int2*  epk  = (int2*)(ws + EPK_OFF);
  int*   cnt  = (int*)(ws + CNT_OFF);
  int*   off  = (int*)(ws + OFF_OFF);
  int*   cur  = (int*)(ws + CUR_OFF);
  float* wc   = ws + WC_OFF;

  hipMemsetAsync(cnt, 0, NKEY * sizeof(int), stream);

  wcoef_kernel<<<1, 64, 0, stream>>>(as_seq0, as_last_seq0, as_res0, as_last_res0,
                                     as_seq1, as_last_seq1, as_last_res1, wc);

  hid_kernel<<<NNODES / 4, 256, 0, stream>>>(node_feats, node_types, type_W, type_b,
                                             aW0, ab0, aW1, ab1, xp);

  // edge bucketing: hist -> scan -> scatter (12.5K L2-resident cursors)
  histb_kernel<<<dim3(64, 4), 256, 0, stream>>>(adj_rows, cnt);
  scanb_kernel<<<1, 256, 0, stream>>>(cnt, off, cur);
  binscatter_kernel<<<dim3(NEDGE / 256, 4), 256, 0, stream>>>(adj_rows, adj_cols, adj_vals,
                                                              cur, epk);

  // SpMM stages: on-the-fly LDS row-sort + register accumulation
  st1_kernel<<<NB, 256, 0, stream>>>(off, cnt, epk, xp, wc, sp, cres, cz0, cz1);
  st2_kernel<<<NB, 256, 0, stream>>>(off, cnt, epk, sp, wc, cres, cz0, cz1);
  st3_kernel<<<NB, 256, 0, stream>>>(off, cnt, epk, cres, wc, cz0);

  final_kernel<<<NNODES / 4, 256, 0, stream>>>(cz0, cz1,
                                               attn1_W, attn1_b, attn2_W, attn2_b,
                                               cls_W, cls_b, out);
}